// Round 15
// baseline (110.914 us; speedup 1.0000x reference)
//
#include <hip/hip_runtime.h>
#include <hip/hip_fp16.h>

typedef _Float16 f16x8 __attribute__((ext_vector_type(8)));
typedef float f32x4 __attribute__((ext_vector_type(4)));

#define AS1 __attribute__((address_space(1)))
#define AS3 __attribute__((address_space(3)))

__device__ __forceinline__ unsigned short f2h(float f) {
  _Float16 h = (_Float16)f;
  return __builtin_bit_cast(unsigned short, h);
}

// ---------------------------------------------------------------------------
// Prep: W2 [J][256][256] f32 -> w2t [j*2+ch][4 slices][128 cols][128B] f16,
// swizzled: byte(n, kk) = n*128 + ((2*kk) ^ ((n&7)<<4)), n in [0,128),
// kk in [0,64). Linear image for global_load_lds + conflict-free ds_read_b128.
// ---------------------------------------------------------------------------
__global__ __launch_bounds__(256) void prep_w2t(const float* __restrict__ W2,
                                                unsigned char* __restrict__ w2t) {
  const int s = blockIdx.x;    // k-slice 0..3
  const int jc = blockIdx.y;   // j*2+ch
  const int j = jc >> 1, ch = jc & 1;
  const int t = threadIdx.x;
  __shared__ unsigned short lds[64 * 136];  // [kk][n], padded

  const float* src = W2 + (size_t)j * 65536 + (size_t)(s * 64) * 256 + ch * 128;
#pragma unroll
  for (int i = 0; i < 8; ++i) {
    const int idx4 = i * 256 + t;        // 2048 float4s = 64kk x 128n
    const int kk = idx4 >> 5;
    const int n4 = (idx4 & 31) << 2;
    const float4 v = *reinterpret_cast<const float4*>(src + kk * 256 + n4);
    unsigned short* p = &lds[kk * 136 + n4];
    p[0] = f2h(v.x); p[1] = f2h(v.y); p[2] = f2h(v.z); p[3] = f2h(v.w);
  }
  __syncthreads();

  unsigned char* dst = w2t + (((size_t)jc * 4 + s) << 14);
#pragma unroll
  for (int i = 0; i < 4; ++i) {
    const int slot = i * 256 + t;        // 1024 16B slots
    const int n = slot >> 3, u = slot & 7;
    const int kk0 = (u ^ (n & 7)) << 3;  // 8 consecutive kk per slot
    unsigned int w[4];
#pragma unroll
    for (int q = 0; q < 4; ++q) {
      const unsigned int lo = lds[(kk0 + 2 * q + 0) * 136 + n];
      const unsigned int hi = lds[(kk0 + 2 * q + 1) * 136 + n];
      w[q] = lo | (hi << 16);
    }
    *reinterpret_cast<uint4*>(dst + slot * 16) = make_uint4(w[0], w[1], w[2], w[3]);
  }
}

// ---------------------------------------------------------------------------
// JIT layer-1 in packed f16: A-fragments for 4 m-frags (64 rows) of one kf.
// W1 f16 LDS layout: stream c at c*512 + k*2 ; b1 at 2048 + k*2.
// 5 broadcast ds_read_b128 serve all 4 m-frags.
// ---------------------------------------------------------------------------
__device__ __forceinline__ void jit_af4(const unsigned char* w1base,
                                        const __half2 xh[4][4], int kf,
                                        f16x8 af[4]) {
  const int o = kf << 6;
  const uint4 w0 = *reinterpret_cast<const uint4*>(w1base + o);
  const uint4 w1v = *reinterpret_cast<const uint4*>(w1base + 512 + o);
  const uint4 w2v = *reinterpret_cast<const uint4*>(w1base + 1024 + o);
  const uint4 w3v = *reinterpret_cast<const uint4*>(w1base + 1536 + o);
  const uint4 bb = *reinterpret_cast<const uint4*>(w1base + 2048 + o);
  const __half2 one2 = __float2half2_rn(1.0f);
  const __half2 nl2e = __float2half2_rn(-1.44269504f);  // -log2(e)
#pragma unroll
  for (int mf = 0; mf < 4; ++mf) {
    unsigned int hw[4];
#pragma unroll
    for (int p = 0; p < 4; ++p) {
      __half2 z = __builtin_bit_cast(__half2, (&bb.x)[p]);
      z = __hfma2(xh[mf][0], __builtin_bit_cast(__half2, (&w0.x)[p]), z);
      z = __hfma2(xh[mf][1], __builtin_bit_cast(__half2, (&w1v.x)[p]), z);
      z = __hfma2(xh[mf][2], __builtin_bit_cast(__half2, (&w2v.x)[p]), z);
      z = __hfma2(xh[mf][3], __builtin_bit_cast(__half2, (&w3v.x)[p]), z);
      // silu(z) = z / (1 + exp(-z)) ; exp(-z) = 2^(z * -log2e)
      const __half2 e = h2exp2(__hmul2(z, nl2e));
      const __half2 sig = h2rcp(__hadd2(one2, e));
      const __half2 h = __hmul2(z, sig);
      hw[p] = __builtin_bit_cast(unsigned int, h);
    }
    af[mf] = __builtin_bit_cast(f16x8, make_uint4(hw[0], hw[1], hw[2], hw[3]));
  }
}

// ---------------------------------------------------------------------------
// Main fused kernel: 64x64 wave tiles SPILL-FREE. 4096 blocks x 256 threads
// (4 waves = 2 row-groups x 2 col-groups); block tile 128 rows x 128 cols of
// one (j,ch). __launch_bounds__(256,2) lifts the VGPR cap to 256 (R13/R14's
// 128-cap spilled acc). LDS 68.6KB -> 2 blocks/CU. W2 panel staged ONCE,
// slice-ordered (16 instrs, 4/slice); counted vmcnt 12/8/4/0 + barrier.
// Each B ds_read feeds 4 MFMAs -> per-wave B-side LDS bytes halved vs 32x128.
// ---------------------------------------------------------------------------
__global__ __launch_bounds__(256, 2) void fused_mlp(
    const float* __restrict__ input, const int* __restrict__ validity,
    const float* __restrict__ W1, const float* __restrict__ b1,
    const float* __restrict__ b2, const unsigned char* __restrict__ w2t,
    float* __restrict__ out) {
  // 64KB W2 + 2KB W1(f16) + 0.5KB b1(f16) + 0.5KB b2(f32) = 68608 bytes.
  __shared__ __align__(16) unsigned char smem[68608];
  const int bid = blockIdx.x;
  const int by = bid & 63;             // j*2+ch ; XCD = bid%8 (panel-affine)
  const int bx = bid >> 6;             // row tile 0..63 (128 rows each)
  const int j = by >> 1, ch = by & 1;
  const int tid = threadIdx.x;
  const int wid = tid >> 6;            // 0..3
  const int lane = tid & 63;
  const int l15 = lane & 15, lg = lane >> 4;
  const int wr = wid >> 1, wc = wid & 1;
  const int rowbase = (bx << 7) + (wr << 6);  // wave owns 64 rows

  // ---- prologue global loads: ALL issued before the stages ----
  float xr[4][4];
#pragma unroll
  for (int mf = 0; mf < 4; ++mf) {
    const int row = rowbase + mf * 16 + l15;
    const float* ip = input + ((size_t)row * 32 + j) * 3;
    xr[mf][0] = ip[0]; xr[mf][1] = ip[1]; xr[mf][2] = ip[2];
    xr[mf][3] = (float)validity[row * 32 + j];
  }
  float4 wa = make_float4(0.f, 0.f, 0.f, 0.f);
  float4 wb = make_float4(0.f, 0.f, 0.f, 0.f);
  if (tid < 128) {            // W1: 1024 f32
    const float* ws = W1 + (j << 10) + (tid << 3);
    wa = *reinterpret_cast<const float4*>(ws);
    wb = *reinterpret_cast<const float4*>(ws + 4);
  } else if (tid < 160) {     // b1: 256 f32
    const float* ws = b1 + (j << 8) + ((tid - 128) << 3);
    wa = *reinterpret_cast<const float4*>(ws);
    wb = *reinterpret_cast<const float4*>(ws + 4);
  } else if (tid < 192) {     // b2 (this ch half): 128 f32, stays f32
    wa = *reinterpret_cast<const float4*>(b2 + (j << 8) + (ch << 7) + ((tid - 160) << 2));
  }

  // ---- single-shot stage of the 4 W2 slices, slice-ordered (4 instrs/slice)
  const unsigned char* w2tj = w2t + ((size_t)by << 16);
#pragma unroll
  for (int it = 0; it < 16; ++it) {
    const int off = ((it << 2) + wid) << 10;  // 1KB per wave-instr, in order
    __builtin_amdgcn_global_load_lds(
        (const AS1 unsigned int*)(w2tj + off + lane * 16),
        (AS3 unsigned int*)(smem + off), 16, 0, 0);
  }

  // ---- W1/b1 (as f16) + b2 (f32) -> LDS params @65536 ----
  if (tid < 160) {
    f16x8 hv;
    hv[0] = (_Float16)wa.x; hv[1] = (_Float16)wa.y;
    hv[2] = (_Float16)wa.z; hv[3] = (_Float16)wa.w;
    hv[4] = (_Float16)wb.x; hv[5] = (_Float16)wb.y;
    hv[6] = (_Float16)wb.z; hv[7] = (_Float16)wb.w;
    *reinterpret_cast<f16x8*>(smem + 65536 + (tid << 4)) = hv;
  } else if (tid < 192) {
    *reinterpret_cast<float4*>(smem + 65536 + 2560 + ((tid - 160) << 4)) = wa;
  }

  // x -> packed f16 splats (consumes xr before the barrier)
  __half2 xh[4][4];
#pragma unroll
  for (int mf = 0; mf < 4; ++mf)
#pragma unroll
    for (int c = 0; c < 4; ++c) xh[mf][c] = __float2half2_rn(xr[mf][c]);

  asm volatile("s_waitcnt lgkmcnt(0)" ::: "memory");  // param ds_writes visible
  __builtin_amdgcn_s_barrier();

  // ---- precomputed LDS bases; loop reads use immediate offsets ----
  const unsigned char* w1base = smem + 65536 + (lg << 4);
  const unsigned char* b2base = smem + 65536 + 2560 + (wc << 8) + (l15 << 2);
  const int n0 = (wc << 6) + l15;                 // col within 128 (nf adds 16)
  const int q0 = (lg << 4) ^ ((l15 & 7) << 4);
  const unsigned char* rA = smem + n0 * 128 + q0;
  const unsigned char* rB = smem + n0 * 128 + (q0 ^ 64);

  // acc init = bias (broadcast read from LDS)
  f32x4 acc[4][4];
#pragma unroll
  for (int nf = 0; nf < 4; ++nf) {
    const float b = *reinterpret_cast<const float*>(b2base + (nf << 6));
#pragma unroll
    for (int mf = 0; mf < 4; ++mf) acc[mf][nf] = f32x4{b, b, b, b};
  }

  const size_t colbase = (size_t)(j << 8) + (ch << 7) + n0;
  f16x8 af[4];

#pragma unroll
  for (int s = 0; s < 4; ++s) {
    jit_af4(w1base, xh, 2 * s, af);

    // slice s staged? counted vmcnt: 4 stage-instrs per remaining slice
    if (s == 0)      asm volatile("s_waitcnt vmcnt(12)" ::: "memory");
    else if (s == 1) asm volatile("s_waitcnt vmcnt(8)" ::: "memory");
    else if (s == 2) asm volatile("s_waitcnt vmcnt(4)" ::: "memory");
    else             asm volatile("s_waitcnt vmcnt(0)" ::: "memory");
    __builtin_amdgcn_s_barrier();

    const int base = s << 14;
    __builtin_amdgcn_s_setprio(1);
#pragma unroll
    for (int nf = 0; nf < 4; ++nf) {
      const f16x8 bf0 = *reinterpret_cast<const f16x8*>(rA + base + nf * 2048);
#pragma unroll
      for (int mf = 0; mf < 4; ++mf)
        acc[mf][nf] = __builtin_amdgcn_mfma_f32_16x16x32_f16(af[mf], bf0,
                                                             acc[mf][nf], 0, 0, 0);
    }
    __builtin_amdgcn_s_setprio(0);

    jit_af4(w1base, xh, 2 * s + 1, af);
    __builtin_amdgcn_s_setprio(1);
#pragma unroll
    for (int nf = 0; nf < 4; ++nf) {
      const f16x8 bf1 = *reinterpret_cast<const f16x8*>(rB + base + nf * 2048);
#pragma unroll
      for (int mf = 0; mf < 4; ++mf)
        acc[mf][nf] = __builtin_amdgcn_mfma_f32_16x16x32_f16(af[mf], bf1,
                                                             acc[mf][nf], 0, 0, 0);
    }
    __builtin_amdgcn_s_setprio(0);
  }

  // ---- epilogue (free-running; no barrier since last sync) ----
#pragma unroll
  for (int mf = 0; mf < 4; ++mf) {
#pragma unroll
    for (int r = 0; r < 4; ++r) {
      const int row = rowbase + mf * 16 + (lg << 2) + r;
      float* pr = out + (size_t)row * 8192 + colbase;
#pragma unroll
      for (int nf = 0; nf < 4; ++nf) pr[nf << 4] = acc[mf][nf][r];
    }
  }
}

extern "C" void kernel_launch(void* const* d_in, const int* in_sizes, int n_in,
                              void* d_out, int out_size, void* d_ws, size_t ws_size,
                              hipStream_t stream) {
  (void)in_sizes; (void)n_in; (void)out_size; (void)ws_size;
  const float* input    = (const float*)d_in[0];
  const int*   validity = (const int*)d_in[1];
  const float* W1       = (const float*)d_in[2];
  const float* b1       = (const float*)d_in[3];
  const float* W2       = (const float*)d_in[4];
  const float* b2       = (const float*)d_in[5];
  float* out = (float*)d_out;
  unsigned char* w2t = (unsigned char*)d_ws;  // 4 MB: 64 x 64KB

  prep_w2t<<<dim3(4, 64), 256, 0, stream>>>(W2, w2t);
  fused_mlp<<<4096, 256, 0, stream>>>(input, validity, W1, b1, b2, w2t, out);
}

// Round 16
// 79.474 us; speedup vs baseline: 1.3956x; 1.3956x over previous
//
#include <hip/hip_runtime.h>
#include <hip/hip_fp16.h>

typedef _Float16 f16x8 __attribute__((ext_vector_type(8)));
typedef float f32x4 __attribute__((ext_vector_type(4)));

#define AS1 __attribute__((address_space(1)))
#define AS3 __attribute__((address_space(3)))

__device__ __forceinline__ unsigned short f2h(float f) {
  _Float16 h = (_Float16)f;
  return __builtin_bit_cast(unsigned short, h);
}

// ---------------------------------------------------------------------------
// Prep: W2 [J][256][256] f32 -> w2t [j*2+ch][4 slices][128 cols][128B] f16,
// swizzled: byte(n, kk) = n*128 + ((2*kk) ^ ((n&7)<<4)), n in [0,128),
// kk in [0,64). Linear image for global_load_lds + conflict-free ds_read_b128.
// ---------------------------------------------------------------------------
__global__ __launch_bounds__(256) void prep_w2t(const float* __restrict__ W2,
                                                unsigned char* __restrict__ w2t) {
  const int s = blockIdx.x;    // k-slice 0..3
  const int jc = blockIdx.y;   // j*2+ch
  const int j = jc >> 1, ch = jc & 1;
  const int t = threadIdx.x;
  __shared__ unsigned short lds[64 * 136];  // [kk][n], padded

  const float* src = W2 + (size_t)j * 65536 + (size_t)(s * 64) * 256 + ch * 128;
#pragma unroll
  for (int i = 0; i < 8; ++i) {
    const int idx4 = i * 256 + t;        // 2048 float4s = 64kk x 128n
    const int kk = idx4 >> 5;
    const int n4 = (idx4 & 31) << 2;
    const float4 v = *reinterpret_cast<const float4*>(src + kk * 256 + n4);
    unsigned short* p = &lds[kk * 136 + n4];
    p[0] = f2h(v.x); p[1] = f2h(v.y); p[2] = f2h(v.z); p[3] = f2h(v.w);
  }
  __syncthreads();

  unsigned char* dst = w2t + (((size_t)jc * 4 + s) << 14);
#pragma unroll
  for (int i = 0; i < 4; ++i) {
    const int slot = i * 256 + t;        // 1024 16B slots
    const int n = slot >> 3, u = slot & 7;
    const int kk0 = (u ^ (n & 7)) << 3;  // 8 consecutive kk per slot
    unsigned int w[4];
#pragma unroll
    for (int q = 0; q < 4; ++q) {
      const unsigned int lo = lds[(kk0 + 2 * q + 0) * 136 + n];
      const unsigned int hi = lds[(kk0 + 2 * q + 1) * 136 + n];
      w[q] = lo | (hi << 16);
    }
    *reinterpret_cast<uint4*>(dst + slot * 16) = make_uint4(w[0], w[1], w[2], w[3]);
  }
}

// ---------------------------------------------------------------------------
// JIT layer-1 in packed f16: A-fragments (2 m-frags) for one kf.
// W1 f16 layout in LDS: stream c at c*512 + k*2 ; b1 at 2048 + k*2.
// ---------------------------------------------------------------------------
__device__ __forceinline__ void jit_af(const unsigned char* w1base,
                                       const __half2 xh[2][4], int kf,
                                       f16x8 af[2]) {
  const int o = kf << 6;
  const uint4 w0 = *reinterpret_cast<const uint4*>(w1base + o);
  const uint4 w1v = *reinterpret_cast<const uint4*>(w1base + 512 + o);
  const uint4 w2v = *reinterpret_cast<const uint4*>(w1base + 1024 + o);
  const uint4 w3v = *reinterpret_cast<const uint4*>(w1base + 1536 + o);
  const uint4 bb = *reinterpret_cast<const uint4*>(w1base + 2048 + o);
  const __half2 one2 = __float2half2_rn(1.0f);
  const __half2 nl2e = __float2half2_rn(-1.44269504f);  // -log2(e)
#pragma unroll
  for (int mf = 0; mf < 2; ++mf) {
    unsigned int hw[4];
#pragma unroll
    for (int p = 0; p < 4; ++p) {
      __half2 z = __builtin_bit_cast(__half2, (&bb.x)[p]);
      z = __hfma2(xh[mf][0], __builtin_bit_cast(__half2, (&w0.x)[p]), z);
      z = __hfma2(xh[mf][1], __builtin_bit_cast(__half2, (&w1v.x)[p]), z);
      z = __hfma2(xh[mf][2], __builtin_bit_cast(__half2, (&w2v.x)[p]), z);
      z = __hfma2(xh[mf][3], __builtin_bit_cast(__half2, (&w3v.x)[p]), z);
      // silu(z) = z / (1 + exp(-z)) ; exp(-z) = 2^(z * -log2e)
      const __half2 e = h2exp2(__hmul2(z, nl2e));
      const __half2 sig = h2rcp(__hadd2(one2, e));
      const __half2 h = __hmul2(z, sig);
      hw[p] = __builtin_bit_cast(unsigned int, h);
    }
    const uint4 u4 = make_uint4(hw[0], hw[1], hw[2], hw[3]);
    af[mf] = __builtin_bit_cast(f16x8, u4);
  }
}

// ---------------------------------------------------------------------------
// Main fused kernel (round-7 verified optimum). 2048 blocks, 512 threads =
// 8 waves, wave tile 32 rows x 128 cols. Block tile 256 rows x 128 cols of
// one (j,ch). 1D grid: by = bid&63 -> XCD = bid%8 (panel-affine L2 locality).
// All 4 K-slices (64KB) staged ONCE at block start, slice-ordered; per-slice
// readiness via counted vmcnt + barrier. No restage, no lgkm drains.
// ---------------------------------------------------------------------------
__global__ __launch_bounds__(512, 4) void fused_mlp(
    const float* __restrict__ input, const int* __restrict__ validity,
    const float* __restrict__ W1, const float* __restrict__ b1,
    const float* __restrict__ b2, const unsigned char* __restrict__ w2t,
    float* __restrict__ out) {
  // 64KB W2 + 2KB W1(f16) + 0.5KB b1(f16) + 0.5KB b2(f32) = 68608 bytes.
  __shared__ __align__(16) unsigned char smem[68608];
  const int bid = blockIdx.x;
  const int by = bid & 63;             // j*2+ch ; XCD = bid%8 (panel-affine)
  const int bx = bid >> 6;             // row tile 0..31 (256 rows each)
  const int j = by >> 1, ch = by & 1;
  const int tid = threadIdx.x;
  const int wid = tid >> 6;
  const int lane = tid & 63;
  const int l15 = lane & 15, lg = lane >> 4;
  const int rowbase = (bx << 8) + (wid << 5);  // wave owns 32 rows

  // ---- prologue global loads: ALL issued before the stages ----
  float xr[2][4];
#pragma unroll
  for (int mf = 0; mf < 2; ++mf) {
    const int row = rowbase + mf * 16 + l15;
    const float* ip = input + ((size_t)row * 32 + j) * 3;
    xr[mf][0] = ip[0]; xr[mf][1] = ip[1]; xr[mf][2] = ip[2];
    xr[mf][3] = (float)validity[row * 32 + j];
  }
  float4 wa = make_float4(0.f, 0.f, 0.f, 0.f);
  float4 wb = make_float4(0.f, 0.f, 0.f, 0.f);
  if (tid < 128) {            // W1: 1024 f32
    const float* ws = W1 + (j << 10) + (tid << 3);
    wa = *reinterpret_cast<const float4*>(ws);
    wb = *reinterpret_cast<const float4*>(ws + 4);
  } else if (tid < 160) {     // b1: 256 f32
    const float* ws = b1 + (j << 8) + ((tid - 128) << 3);
    wa = *reinterpret_cast<const float4*>(ws);
    wb = *reinterpret_cast<const float4*>(ws + 4);
  } else if (tid < 192) {     // b2 (this ch half): 128 f32, stays f32
    wa = *reinterpret_cast<const float4*>(b2 + (j << 8) + (ch << 7) + ((tid - 160) << 2));
  }

  // ---- single-shot stage of the 4 W2 slices, slice-ordered (2 instrs/slice)
  const unsigned char* w2tj = w2t + ((size_t)by << 16);
#pragma unroll
  for (int it = 0; it < 8; ++it) {
    const int off = ((it << 3) + wid) << 10;  // 1KB per wave-instr
    __builtin_amdgcn_global_load_lds(
        (const AS1 unsigned int*)(w2tj + off + lane * 16),
        (AS3 unsigned int*)(smem + off), 16, 0, 0);
  }

  // ---- W1/b1 (as f16) + b2 (f32) -> LDS ----
  if (tid < 160) {
    f16x8 hv;
    hv[0] = (_Float16)wa.x; hv[1] = (_Float16)wa.y;
    hv[2] = (_Float16)wa.z; hv[3] = (_Float16)wa.w;
    hv[4] = (_Float16)wb.x; hv[5] = (_Float16)wb.y;
    hv[6] = (_Float16)wb.z; hv[7] = (_Float16)wb.w;
    *reinterpret_cast<f16x8*>(smem + 65536 + (tid << 4)) = hv;
  } else if (tid < 192) {
    *reinterpret_cast<float4*>(smem + 65536 + 2560 + ((tid - 160) << 4)) = wa;
  }

  // x -> packed f16 splats
  __half2 xh[2][4];
#pragma unroll
  for (int mf = 0; mf < 2; ++mf)
#pragma unroll
    for (int c = 0; c < 4; ++c) xh[mf][c] = __float2half2_rn(xr[mf][c]);

  asm volatile("s_waitcnt lgkmcnt(0)" ::: "memory");  // W1 ds_writes visible
  __builtin_amdgcn_s_barrier();

  // ---- precomputed LDS bases; loop reads use immediate offsets ----
  const unsigned char* w1base = smem + 65536 + (lg << 4);
  const unsigned char* b2base = smem + 65536 + 2560 + (l15 << 2);
  const int q0 = (lg << 4) ^ ((l15 & 7) << 4);
  const unsigned char* rA = smem + l15 * 128 + q0;
  const unsigned char* rB = smem + l15 * 128 + (q0 ^ 64);

  // acc init = bias (broadcast read from LDS)
  f32x4 acc[2][8];
#pragma unroll
  for (int nf = 0; nf < 8; ++nf) {
    const float b = *reinterpret_cast<const float*>(b2base + (nf << 6));
    acc[0][nf] = f32x4{b, b, b, b};
    acc[1][nf] = acc[0][nf];
  }

  const size_t colbase = (size_t)(j << 8) + (ch << 7) + l15;
  f16x8 af[2];

#pragma unroll
  for (int s = 0; s < 4; ++s) {
    jit_af(w1base, xh, 2 * s, af);

    // slice s staged? counted vmcnt: 2 stage-instrs per remaining slice
    if (s == 0)      asm volatile("s_waitcnt vmcnt(6)" ::: "memory");
    else if (s == 1) asm volatile("s_waitcnt vmcnt(4)" ::: "memory");
    else if (s == 2) asm volatile("s_waitcnt vmcnt(2)" ::: "memory");
    else             asm volatile("s_waitcnt vmcnt(0)" ::: "memory");
    __builtin_amdgcn_s_barrier();

    const int base = s << 14;
    __builtin_amdgcn_s_setprio(1);
#pragma unroll
    for (int nf = 0; nf < 8; ++nf) {
      const f16x8 bf0 = *reinterpret_cast<const f16x8*>(rA + base + nf * 2048);
      acc[0][nf] = __builtin_amdgcn_mfma_f32_16x16x32_f16(af[0], bf0, acc[0][nf], 0, 0, 0);
      acc[1][nf] = __builtin_amdgcn_mfma_f32_16x16x32_f16(af[1], bf0, acc[1][nf], 0, 0, 0);
    }
    __builtin_amdgcn_s_setprio(0);

    jit_af(w1base, xh, 2 * s + 1, af);
    __builtin_amdgcn_s_setprio(1);
#pragma unroll
    for (int nf = 0; nf < 8; ++nf) {
      const f16x8 bf1 = *reinterpret_cast<const f16x8*>(rB + base + nf * 2048);
      acc[0][nf] = __builtin_amdgcn_mfma_f32_16x16x32_f16(af[0], bf1, acc[0][nf], 0, 0, 0);
      acc[1][nf] = __builtin_amdgcn_mfma_f32_16x16x32_f16(af[1], bf1, acc[1][nf], 0, 0, 0);
    }
    __builtin_amdgcn_s_setprio(0);
  }

  // ---- epilogue (free-running; no barrier since last sync) ----
#pragma unroll
  for (int mf = 0; mf < 2; ++mf) {
#pragma unroll
    for (int r = 0; r < 4; ++r) {
      const int row = rowbase + mf * 16 + (lg << 2) + r;
      float* pr = out + (size_t)row * 8192 + colbase;
#pragma unroll
      for (int nf = 0; nf < 8; ++nf) pr[nf << 4] = acc[mf][nf][r];
    }
  }
}

extern "C" void kernel_launch(void* const* d_in, const int* in_sizes, int n_in,
                              void* d_out, int out_size, void* d_ws, size_t ws_size,
                              hipStream_t stream) {
  (void)in_sizes; (void)n_in; (void)out_size; (void)ws_size;
  const float* input    = (const float*)d_in[0];
  const int*   validity = (const int*)d_in[1];
  const float* W1       = (const float*)d_in[2];
  const float* b1       = (const float*)d_in[3];
  const float* W2       = (const float*)d_in[4];
  const float* b2       = (const float*)d_in[5];
  float* out = (float*)d_out;
  unsigned char* w2t = (unsigned char*)d_ws;  // 4 MB: 64 x 64KB

  prep_w2t<<<dim3(4, 64), 256, 0, stream>>>(W2, w2t);
  fused_mlp<<<2048, 512, 0, stream>>>(input, validity, W1, b1, b2, w2t, out);
}